// Round 1
// 805.573 us; speedup vs baseline: 1.1703x; 1.1703x over previous
//
#include <hip/hip_runtime.h>
#include <hip/hip_fp16.h>
#include <math.h>

// LPKT R9: latency-attack on the recurrent kernel.
// - All in-loop barriers are lgkmcnt-only (asm s_waitcnt lgkmcnt(0) + raw s_barrier):
//   no vmcnt(0) drain -> prefetched global loads stay in flight across barriers.
// - qm-row / PRE-row prefetched one full iteration ahead (e_data cached in LDS,
//   s_q triple-buffered), so chained global latency is off the critical path.
// - h@W4h MFMA chain + row-128 logit hoisted to iteration top (inputs stable since
//   prev-iter barriers) -> latency hides under the P1 GEMV; old B5 removed.
// - LG+P3 merged into one phase (per-wave k-quarter LG recompute + readlane GEMV);
//   old B2 removed.  y-epilogue (old ph8/B8/ph9) moved to new k4_y kernel reading
//   an HTV history buffer (fp16) -> old B8 removed.  8 barriers/step -> 5.
// - k1/k2 re-tiled 16->4 timesteps/block (more blocks, latency-bound prep).

#define BB   64
#define SS   100
#define DK   128
#define NTH  512

// ws dword offsets
#define OFF_PW1AB   0
#define OFF_PW23ABC 16384
#define OFF_PW4I    65536
#define OFF_PW5A    73728
#define OFF_PW23D   81920
#define OFF_PW4L    98304
#define OFF_PW5B    106496
#define OFF_AFRAG   114688
#define OFF_S1      122880
#define OFF_AL      123008
#define OFF_PRE     532608
#define OFF_HTV     2171008   // 64*99*128 halves = 405504 dwords

typedef __attribute__((ext_vector_type(16))) float floatx16;
typedef __attribute__((ext_vector_type(8)))  short short8v;

__device__ __forceinline__ float frcp(float x) { return __builtin_amdgcn_rcpf(x); }
__device__ __forceinline__ float fsig(float x) { float t = __expf(-x); return frcp(1.0f + t); }
__device__ __forceinline__ float ftanh(float x) {
    x = fminf(20.0f, fmaxf(-20.0f, x));
    float t = __expf(-2.0f * x);
    return (1.0f - t) * frcp(1.0f + t);
}
__device__ __forceinline__ float rlf(float v, int s) {
    return __int_as_float(__builtin_amdgcn_readlane(__float_as_int(v), s));
}
__device__ __forceinline__ unsigned bfbits(float x) {
    unsigned u = __float_as_uint(x);
    return (u + 0x7fffu + ((u >> 16) & 1u)) >> 16;
}
__device__ __forceinline__ unsigned pack2(float a, float b) {
    return bfbits(a) | (bfbits(b) << 16);
}
__device__ __forceinline__ float blo(unsigned u) { return __uint_as_float(u << 16); }
__device__ __forceinline__ float bhi(unsigned u) { return __uint_as_float(u & 0xffff0000u); }

// lgkm-only workgroup barrier: LDS-producer drain + raw barrier. No vmcnt drain:
// global loads are consumed via register deps (compiler inserts vmcnt at use);
// global stores have no in-kernel readers. Memory clobbers pin LDS ops on both sides.
__device__ __forceinline__ void wg_barrier() {
    asm volatile("s_waitcnt lgkmcnt(0)" ::: "memory");
    __builtin_amdgcn_s_barrier();
    asm volatile("" ::: "memory");
}

// ---- K0: weight packing (unchanged) ------------------------------------------
__global__ void k0_prep(const float* __restrict__ W1, const float* __restrict__ W2,
                        const float* __restrict__ W3, const float* __restrict__ W4,
                        const float* __restrict__ W5, unsigned* __restrict__ ws) {
    int g = blockIdx.x * blockDim.x + threadIdx.x;
    if (g < 16384) {
        int s = g >> 7, d = g & 127;
        ws[OFF_PW1AB + g] = pack2(W1[(2*s)*DK + d], W1[(2*s+1)*DK + d]);
    } else if (g < 65536) {
        int i = g - 16384; int s = i >> 8, j = i & 255;
        const float* M = (j < 128) ? W2 : W3; int jj = j & 127;
        ws[g] = pack2(M[(2*s)*DK + jj], M[(2*s+1)*DK + jj]);
    } else if (g < 73728) {
        int i = g - 65536; int s = i >> 7, j = i & 127;
        ws[g] = pack2(W4[(256+2*s)*DK + j], W4[(257+2*s)*DK + j]);
    } else if (g < 81920) {
        int i = g - 73728; int s = i >> 7, j = i & 127;
        ws[g] = pack2(W5[(2*s)*DK + j], W5[(2*s+1)*DK + j]);
    } else if (g < 98304) {
        int i = g - 81920; int s = i & 31, j = (i >> 5) & 255, kh = i >> 13;
        int k0 = 64*kh + 2*s;
        const float* M = (j < 128) ? W2 : W3; int jj = j & 127;
        ws[g] = pack2(M[(384+k0)*DK + jj], M[(385+k0)*DK + jj]);
    } else if (g < 106496) {
        int i = g - 98304; int s = i & 15, j = (i >> 4) & 127, kq = i >> 11;
        int k0 = 32*kq + 2*s;
        ws[g] = pack2(W4[(128+k0)*DK + j], W4[(129+k0)*DK + j]);
    } else if (g < 114688) {
        int i = g - 106496; int s = i & 15, j = (i >> 4) & 127, kq = i >> 11;
        int k0 = 32*kq + 2*s;
        ws[g] = pack2(W5[(128+k0)*DK + j], W5[(129+k0)*DK + j]);
    } else if (g < 122880) {
        int i = g - 114688;
        int gg = i >> 11, kb = (i >> 8) & 7, ln = (i >> 2) & 63, c = i & 3;
        int m = ln & 31, hp = ln >> 5;
        int k0 = 16*kb + 8*hp + 2*c;
        ws[g] = pack2(W4[k0*DK + 32*gg + m], W4[(k0+1)*DK + 32*gg + m]);
    } else if (g < 123008) {
        int d = g - 122880;
        float z = 0.f;
        for (int k = 0; k < 128; k++) z += W1[(256+k)*DK + d];
        ws[g] = __float_as_uint(z);
    }
}

// ---- K1: AL (fp16), 4 timesteps per block ------------------------------------
__global__ __launch_bounds__(128)
void k1_al(const int* __restrict__ e_data, const int* __restrict__ a_data,
           const int* __restrict__ at_data, const float* __restrict__ Ee,
           const float* __restrict__ Eat, const float* __restrict__ b1,
           unsigned* __restrict__ ws) {
    const int b = blockIdx.x, t0 = 4 * blockIdx.y, tid = threadIdx.x;
    __shared__ __align__(16) float s_f[4][256];
    #pragma unroll
    for (int r = 0; r < 8; r++) {
        int id = r * 128 + tid; int i = id >> 8, k = id & 255;
        int t = t0 + i; float v = 0.f;
        if (t <= 98) {
            int e  = e_data[b*SS + t];
            int at = at_data[b*SS + t];
            v = (k < 128) ? Ee[(size_t)e*DK + k] : Eat[(size_t)at*DK + (k-128)];
        }
        s_f[i][k] = v;
    }
    __syncthreads();
    float s1v = __uint_as_float(ws[OFF_S1 + tid]);
    float b1v = b1[tid];
    float z[4];
    #pragma unroll
    for (int i = 0; i < 4; i++) z[i] = 0.f;
    #pragma unroll 2
    for (int s = 0; s < 128; s++) {
        unsigned w = ws[OFF_PW1AB + s*128 + tid];
        float wl = blo(w), wh = bhi(w);
        #pragma unroll
        for (int i = 0; i < 4; i++) {
            float2 f = *(const float2*)&s_f[i][2*s];
            z[i] += f.x*wl + f.y*wh;
        }
    }
    __half* AL = (__half*)(ws + OFF_AL);
    #pragma unroll
    for (int i = 0; i < 4; i++) {
        int t = t0 + i;
        if (t <= 98) {
            float a = (float)a_data[b*SS + t];
            AL[(size_t)(b*SS + t)*DK + tid] = __float2half(z[i] + a*s1v + b1v);
        }
    }
}

// ---- K2: PRE[b][t][512] (fp16), 4 timesteps per block ------------------------
__global__ __launch_bounds__(512)
void k2_pre(const int* __restrict__ e_data, const int* __restrict__ it_data,
            const float* __restrict__ Eit, const float* __restrict__ Ee,
            const float* __restrict__ b2, const float* __restrict__ b3,
            const float* __restrict__ b4, const float* __restrict__ b5,
            unsigned* __restrict__ ws) {
    const int b = blockIdx.x, t0 = 4 * blockIdx.y, tid = threadIdx.x;
    __shared__ __align__(16) float s_g[4][384];
    __shared__ __align__(16) float s_e[4][128];
    const __half* AL = (const __half*)(ws + OFF_AL);
    #pragma unroll
    for (int r = 0; r < 3; r++) {
        int id = r * 512 + tid; int i = id / 384; int k = id - 384*i;
        int t = t0 + i; float v = 0.f;
        if (t <= 98) {
            if (k < 128)      v = (t == 0) ? 0.f : (float)AL[(size_t)(b*SS + t - 1)*DK + k];
            else if (k < 256) v = Eit[(size_t)it_data[b*SS + t]*DK + (k - 128)];
            else              v = (float)AL[(size_t)(b*SS + t)*DK + (k - 256)];
        }
        s_g[i][k] = v;
    }
    {
        int id = tid; int i = id >> 7, k = id & 127;
        int t = t0 + i;
        s_e[i][k] = (t <= 98) ? Ee[(size_t)e_data[b*SS + t + 1]*DK + k] : 0.f;
    }
    __syncthreads();
    __half* PRE = (__half*)(ws + OFF_PRE);
    float z[4];
    #pragma unroll
    for (int i = 0; i < 4; i++) z[i] = 0.f;
    int col; float bb;
    if (tid < 256) {
        int j = tid;
        #pragma unroll 2
        for (int s = 0; s < 192; s++) {
            unsigned w = ws[OFF_PW23ABC + s*256 + j];
            float wl = blo(w), wh = bhi(w);
            #pragma unroll
            for (int i = 0; i < 4; i++) {
                float2 f = *(const float2*)&s_g[i][2*s];
                z[i] += f.x*wl + f.y*wh;
            }
        }
        col = j; bb = (j < 128) ? b2[j] : b3[j - 128];
    } else if (tid < 384) {
        int j = tid - 256;
        #pragma unroll 2
        for (int s = 0; s < 64; s++) {
            unsigned w = ws[OFF_PW4I + s*128 + j];
            float wl = blo(w), wh = bhi(w);
            #pragma unroll
            for (int i = 0; i < 4; i++) {
                float2 f = *(const float2*)&s_g[i][128 + 2*s];
                z[i] += f.x*wl + f.y*wh;
            }
        }
        col = 256 + j; bb = b4[j];
    } else {
        int j = tid - 384;
        #pragma unroll 2
        for (int s = 0; s < 64; s++) {
            unsigned w = ws[OFF_PW5A + s*128 + j];
            float wl = blo(w), wh = bhi(w);
            #pragma unroll
            for (int i = 0; i < 4; i++) {
                float2 f = *(const float2*)&s_e[i][2*s];
                z[i] += f.x*wl + f.y*wh;
            }
        }
        col = 384 + j; bb = b5[j];
    }
    #pragma unroll
    for (int i = 0; i < 4; i++) {
        int t = t0 + i;
        if (t <= 98) PRE[(size_t)(b*SS + t)*512 + col] = __float2half(z[i] + bb);
    }
}

// ---- K3: recurrent kernel ----------------------------------------------------
__global__ __launch_bounds__(NTH, 2)
void lpkt_kernel(const int* __restrict__ e_data, const float* __restrict__ qm,
                 const float* __restrict__ h0, unsigned* __restrict__ ws)
{
    const int b    = blockIdx.x;
    const int tid  = threadIdx.x;
    const int lane = tid & 63;
    const int w    = tid >> 6;
    const int g    = w & 3;            // MFMA d-block
    const int hh   = w >> 2;           // half: cb pair {2hh, 2hh+1}; P1 k-half
    const int h5   = lane >> 5;
    const int l31  = lane & 31;
    const int j1   = tid & 255;        // P1 output col
    const int kq4  = w & 3;            // P3 k-quarter (new mapping)
    const int j4   = ((w >> 2) << 6) + lane;  // P3 output col 0..127

    __shared__ __align__(16) unsigned s_frag[8192];      // 32 KB B-fragments
    __shared__ __align__(16) float s_big[2 * 128 * 34];  // ht-reduce scratch (pad 34, float2-aligned)
    __shared__ __align__(16) float s_pre[2][512];
    __shared__ __align__(16) float s_htv[128];
    __shared__ __align__(16) float s_LG[128];
    __shared__ __align__(16) float s_h128[128];
    __shared__ __align__(16) float s_c[128];
    __shared__ __align__(16) float s_l128[2][128];
    __shared__ __align__(16) float s_red[512];
    __shared__ __align__(16) float s_redE[512];
    __shared__ __align__(16) float s_q[3][160];
    __shared__ int   s_ed[100];
    __shared__ float s_scal[1];

    // ---- permanent registers: afru 32 + w23 32 + w4l 16 + hreg 32 ------------
    uint4    afru[8];
    unsigned w23[32], w4l[16];
    float    hreg[2][16];

    #pragma unroll
    for (int kb = 0; kb < 8; kb++)
        afru[kb] = ((const uint4*)(ws + OFF_AFRAG))[g*512 + kb*64 + lane];
    #pragma unroll
    for (int s = 0; s < 32; s++) w23[s] = ws[OFF_PW23D + ((hh*256 + j1) << 5) + s];
    #pragma unroll
    for (int s = 0; s < 16; s++) w4l[s] = ws[OFF_PW4L + ((kq4*128 + j4) << 4) + s];

    const __half* PRE = (const __half*)(ws + OFF_PRE);
    __half*       HTV = (__half*)(ws + OFF_HTV);

    // ---- prologue: staging + prefetch ----
    if (tid < 100) s_ed[tid] = e_data[b*SS + tid];
    if (tid < 160) { s_q[0][tid] = 0.f; s_q[1][tid] = 0.f; s_q[2][tid] = 0.f; }
    if (tid < 129) {
        s_q[0][tid] = qm[(size_t)e_data[b*SS + 0]*129 + tid];
        s_q[1][tid] = qm[(size_t)e_data[b*SS + 1]*129 + tid];
    }
    s_pre[0][tid] = __half2float(PRE[(size_t)(b*SS)*512 + tid]);
    float  q_pf   = (tid < 129) ? qm[(size_t)e_data[b*SS + 2]*129 + tid] : 0.f;
    __half pre_pf = PRE[(size_t)(b*SS + 1)*512 + tid];

    // ---- prologue: h0 -> regs + frags ----
    #pragma unroll
    for (int i = 0; i < 2; i++) {
        const int cb = 2*hh + i;
        const int n = 32*cb + l31;
        #pragma unroll
        for (int r = 0; r < 16; r++) {
            int d = 32*g + (r&3) + 8*(r>>2) + 4*h5;
            hreg[i][r] = h0[(size_t)n*DK + d];
        }
        #pragma unroll
        for (int q = 0; q < 4; q++) {
            int kb = 2*g + (q>>1);
            int lanep = l31 + ((q&1) << 5);
            int off = (((kb*4 + cb) << 10) + lanep*16 + (h5 << 3)) >> 2;
            uint2 pr = make_uint2(pack2(hreg[i][4*q],   hreg[i][4*q+1]),
                                  pack2(hreg[i][4*q+2], hreg[i][4*q+3]));
            *(uint2*)(s_frag + off) = pr;
        }
    }
    if (tid < 128) s_h128[tid] = h0[(size_t)128*DK + tid];
    __syncthreads();
    {   // vv0 -> s_big ; wave7: q0 sum
        if (w == 7) {
            float v = s_q[0][lane] + s_q[0][64+lane] + ((lane < 32) ? s_q[0][128+lane] : 0.f);
            #pragma unroll
            for (int m = 32; m > 0; m >>= 1) v += __shfl_xor(v, m);
            if (lane == 0) s_scal[0] = v;
        }
        float vv0[16];
        #pragma unroll
        for (int i = 0; i < 2; i++) {
            float qv = s_q[0][32*(2*hh + i) + l31];
            #pragma unroll
            for (int r = 0; r < 16; r++) {
                float p = qv * hreg[i][r];
                vv0[r] = i ? (vv0[r] + p) : p;
            }
        }
        #pragma unroll
        for (int r = 0; r < 16; r++) {
            int d = 32*g + (r&3) + 8*(r>>2) + 4*h5;
            s_big[(hh*128 + d)*34 + l31] = vv0[r];
        }
    }
    __syncthreads();
    if (tid < 128) {
        float a0 = 0.f, a1 = 0.f;
        #pragma unroll
        for (int jj = 0; jj < 16; jj++) {
            float2 x = *(const float2*)&s_big[tid*34 + 2*jj];
            float2 y = *(const float2*)&s_big[(128 + tid)*34 + 2*jj];
            a0 += x.x + x.y; a1 += y.x + y.y;
        }
        s_htv[tid] = (a0 + a1 + s_q[0][128]*s_h128[tid]) * frcp(s_scal[0]);
    }
    __syncthreads();

    // ---- recurrence: 5 lgkm-only barriers per step ----
    for (int t = 0; t < SS - 1; t++) {
        const int pbp = t & 1;
        const float* qc = s_q[t % 3];
        const float* qn = s_q[(t + 1) % 3];

        // ph0: stage prefetched rows; issue next prefetch; qsum; MFMA; logit; P1 GEMV
        if (t + 2 <= 99 && tid < 129) s_q[(t + 2) % 3][tid] = q_pf;
        if (t + 1 <= 98)              s_pre[1 - pbp][tid] = __half2float(pre_pf);
        if (t + 3 <= 99 && tid < 129) q_pf  = qm[(size_t)s_ed[t + 3]*129 + tid];
        if (t + 2 <= 98)              pre_pf = PRE[(size_t)(b*SS + t + 2)*512 + tid];
        if (w == 7) {
            float v = qn[lane] + qn[64 + lane] + ((lane < 32) ? qn[128 + lane] : 0.f);
            #pragma unroll
            for (int m = 32; m > 0; m >>= 1) v += __shfl_xor(v, m);
            if (lane == 0) s_scal[0] = v;
        }
        // hoisted MFMA: inputs are prev-iter s_frag (stable since BD/BE)
        floatx16 am[2];
        #pragma unroll
        for (int i = 0; i < 2; i++) {
            const int cb = 2*hh + i;
            floatx16 a = (floatx16)(0.f);
            #pragma unroll
            for (int kb = 0; kb < 8; kb++) {
                short8v bf = *(const short8v*)((const char*)s_frag +
                               (((kb*4 + cb) << 10) + lane*16));
                a = __builtin_amdgcn_mfma_f32_32x32x16_bf16(
                        __builtin_bit_cast(short8v, afru[kb]), bf, a, 0, 0, 0);
            }
            am[i] = a;
        }
        // hoisted row-128 logit, split across hh halves (k 64*hh..64*hh+63)
        {
            float part = 0.f;
            #pragma unroll
            for (int kbl = 0; kbl < 4; kbl++) {
                const int kb = 4*hh + kbl;
                const int kb0 = 16*kb + 8*h5;
                uint4 u = afru[kb];
                part += s_h128[kb0+0]*blo(u.x) + s_h128[kb0+1]*bhi(u.x);
                part += s_h128[kb0+2]*blo(u.y) + s_h128[kb0+3]*bhi(u.y);
                part += s_h128[kb0+4]*blo(u.z) + s_h128[kb0+5]*bhi(u.z);
                part += s_h128[kb0+6]*blo(u.w) + s_h128[kb0+7]*bhi(u.w);
            }
            part += __shfl_xor(part, 32);
            if (h5 == 0) s_l128[hh][32*g + l31] = part;
        }
        // ph1: P1 = htp . [W2d|W3d] (4-acc)
        {
            float4 fv = ((const float4*)s_htv)[(hh << 4) + (l31 & 15)];
            float z0 = 0.f, z1 = 0.f, z2 = 0.f, z3 = 0.f;
            #pragma unroll
            for (int s = 0; s < 16; s++) {
                float a0 = rlf(fv.x, s), a1 = rlf(fv.y, s);
                float a2 = rlf(fv.z, s), a3 = rlf(fv.w, s);
                unsigned wA = w23[2*s], wB = w23[2*s+1];
                z0 += a0*blo(wA);  z1 += a1*bhi(wA);
                z2 += a2*blo(wB);  z3 += a3*bhi(wB);
            }
            s_red[(hh << 8) + j1] = (z0 + z1) + (z2 + z3);
        }
        wg_barrier();   // BA
        // ph23: per-wave LG (own k-quarter, in-register) + P3 partial GEMV
        {
            const int m = 32*kq4 + l31;
            float z2v = s_red[m]       + s_red[256 + m] + s_pre[pbp][m];
            float z3v = s_red[128 + m] + s_red[384 + m] + s_pre[pbp][128 + m];
            float LGv = fsig(z3v) * (ftanh(z2v) + 1.f) * 0.5f;
            if (w < 4 && h5 == 0) s_LG[m] = LGv;
            float z0 = 0.f, z1 = 0.f, z2 = 0.f, z3 = 0.f;
            #pragma unroll
            for (int s = 0; s < 8; s++) {
                unsigned wA = w4l[2*s], wB = w4l[2*s+1];
                float a0 = rlf(LGv, 4*s+0), a1 = rlf(LGv, 4*s+1);
                float a2 = rlf(LGv, 4*s+2), a3 = rlf(LGv, 4*s+3);
                z0 += a0*blo(wA);  z1 += a1*bhi(wA);
                z2 += a2*blo(wB);  z3 += a3*bhi(wB);
            }
            s_redE[(kq4 << 7) + j4] = (z0 + z1) + (z2 + z3);
        }
        wg_barrier();   // BB
        // ph4: c reduce
        if (tid < 128)
            s_c[tid] = s_redE[tid] + s_redE[128+tid] + s_redE[256+tid] + s_redE[384+tid]
                     + s_pre[pbp][256 + tid];
        wg_barrier();   // BC
        // ph5': gates + h update + vv + frag rewrite + scatter + row-128 update
        {
            float lgv[16], cvv[16], vv[16];
            const float4* LG4 = (const float4*)s_LG;
            const float4* C4  = (const float4*)s_c;
            #pragma unroll
            for (int u = 0; u < 4; u++) {
                float4 lg = LG4[8*g + 2*u + h5];
                float4 cc = C4 [8*g + 2*u + h5];
                lgv[4*u+0]=lg.x; lgv[4*u+1]=lg.y; lgv[4*u+2]=lg.z; lgv[4*u+3]=lg.w;
                cvv[4*u+0]=cc.x; cvv[4*u+1]=cc.y; cvv[4*u+2]=cc.z; cvv[4*u+3]=cc.w;
            }
            #pragma unroll
            for (int i = 0; i < 2; i++) {
                const int cb = 2*hh + i;
                const int n = 32*cb + l31;
                const float qcv = qc[n], qnv = qn[n];
                #pragma unroll
                for (int r = 0; r < 16; r++) {
                    float gg = fsig(am[i][r] + cvv[r]);
                    float hn = qcv*lgv[r] + gg*hreg[i][r];
                    hreg[i][r] = hn;
                    float p = qnv*hn;
                    vv[r] = i ? (vv[r] + p) : p;
                }
            }
            #pragma unroll
            for (int i = 0; i < 2; i++) {
                const int cb = 2*hh + i;
                #pragma unroll
                for (int q = 0; q < 4; q++) {
                    int kb = 2*g + (q>>1);
                    int lanep = l31 + ((q&1) << 5);
                    int off = (((kb*4 + cb) << 10) + lanep*16 + (h5 << 3)) >> 2;
                    uint2 pr = make_uint2(pack2(hreg[i][4*q],   hreg[i][4*q+1]),
                                          pack2(hreg[i][4*q+2], hreg[i][4*q+3]));
                    *(uint2*)(s_frag + off) = pr;
                }
            }
            #pragma unroll
            for (int r = 0; r < 16; r++) {
                int d = 32*g + (r&3) + 8*(r>>2) + 4*h5;
                s_big[(hh*128 + d)*34 + l31] = vv[r];
            }
            if (tid < 128) {
                float gg = fsig(s_l128[0][tid] + s_l128[1][tid] + s_c[tid]);
                s_h128[tid] = qc[128]*s_LG[tid] + gg*s_h128[tid];
            }
        }
        wg_barrier();   // BD
        // ph7: h_tilde reduce + HTV history store (fire-and-forget global store)
        if (tid < 128) {
            float a0 = 0.f, a1 = 0.f;
            #pragma unroll
            for (int jj = 0; jj < 16; jj++) {
                float2 x = *(const float2*)&s_big[tid*34 + 2*jj];
                float2 y = *(const float2*)&s_big[(128 + tid)*34 + 2*jj];
                a0 += x.x + x.y; a1 += y.x + y.y;
            }
            float htvv = (a0 + a1 + qn[128]*s_h128[tid]) * frcp(s_scal[0]);
            s_htv[tid] = htvv;
            HTV[((size_t)b*(SS-1) + t)*128 + tid] = __float2half(htvv);
        }
        wg_barrier();   // BE
    }
}

// ---- K4: y epilogue (parallel over all b,t) ----------------------------------
__global__ __launch_bounds__(128)
void k4_y(const float* __restrict__ W5, float* __restrict__ out,
          const unsigned* __restrict__ ws) {
    const int b = blockIdx.x, t = blockIdx.y, j = threadIdx.x;
    const __half* HTV = (const __half*)(ws + OFF_HTV);
    const __half* PRE = (const __half*)(ws + OFF_PRE);
    __shared__ float s_h[128];
    __shared__ float s_p[2];
    s_h[j] = __half2float(HTV[((size_t)b*(SS-1) + t)*128 + j]);
    __syncthreads();
    float z = __half2float(PRE[(size_t)(b*SS + t)*512 + 384 + j]);
    #pragma unroll 4
    for (int k = 0; k < 128; k++) z += s_h[k] * W5[(size_t)(128 + k)*DK + j];
    float v = fsig(z);
    #pragma unroll
    for (int m = 32; m > 0; m >>= 1) v += __shfl_xor(v, m);
    if ((j & 63) == 0) s_p[j >> 6] = v;
    __syncthreads();
    if (j == 0) {
        out[b*SS + t + 1] = (s_p[0] + s_p[1]) * (1.0f / 128.0f);
        if (t == 0) out[b*SS] = 0.f;
    }
}

extern "C" void kernel_launch(void* const* d_in, const int* in_sizes, int n_in,
                              void* d_out, int out_size, void* d_ws, size_t ws_size,
                              hipStream_t stream) {
    const int*   e_data  = (const int*)d_in[0];
    const int*   a_data  = (const int*)d_in[1];
    const int*   it_data = (const int*)d_in[2];
    const int*   at_data = (const int*)d_in[3];
    const float* qm  = (const float*)d_in[4];
    const float* h0  = (const float*)d_in[5];
    const float* Ee  = (const float*)d_in[6];
    const float* Eat = (const float*)d_in[7];
    const float* Eit = (const float*)d_in[8];
    const float* W1  = (const float*)d_in[9];
    const float* b1  = (const float*)d_in[10];
    const float* W2  = (const float*)d_in[11];
    const float* b2  = (const float*)d_in[12];
    const float* W3  = (const float*)d_in[13];
    const float* b3  = (const float*)d_in[14];
    const float* W4  = (const float*)d_in[15];
    const float* b4  = (const float*)d_in[16];
    const float* W5  = (const float*)d_in[17];
    const float* b5  = (const float*)d_in[18];
    float* out = (float*)d_out;
    unsigned* ws = (unsigned*)d_ws;

    k0_prep<<<dim3((123008 + 255) / 256), dim3(256), 0, stream>>>(W1, W2, W3, W4, W5, ws);
    k1_al<<<dim3(BB, 25), dim3(128), 0, stream>>>(e_data, a_data, at_data, Ee, Eat, b1, ws);
    k2_pre<<<dim3(BB, 25), dim3(512), 0, stream>>>(e_data, it_data, Eit, Ee, b2, b3, b4, b5, ws);
    lpkt_kernel<<<dim3(BB), dim3(NTH), 0, stream>>>(e_data, qm, h0, ws);
    k4_y<<<dim3(BB, SS - 1), dim3(128), 0, stream>>>(W5, out, ws);
}

// Round 2
// 676.730 us; speedup vs baseline: 1.3931x; 1.1904x over previous
//
#include <hip/hip_runtime.h>
#include <hip/hip_fp16.h>
#include <math.h>

// LPKT R10: MFMA-ize the in-loop GEMVs + drop a barrier.
// - P1 (htv . W23d -> 256) done as 8 chained mfma_32x32x16_bf16 per wave
//   (wave = col-block), B-frags (W23d) permanently in registers; A-frag = htv
//   packed bf16 in LDS (s_htvb), broadcast reads. Replaces ~280 VALU instrs.
// - P3 (LG . W4l -> 128): each lane computes ONE LG value (k = 64*(w>>2)+lane),
//   in-wave shfl+pack+ds_bpermute builds bf16 A-frags (no barrier: the wave's
//   k-half lives in its own lanes), 4 chained MFMAs, W4l B-frags in registers.
// - c-reduce barrier (old BC) removed: ph5 reads the 2 redE partials + pre
//   directly (broadcast float4 reads). 5 -> 4 lgkm-only barriers per step.
// - k0 packs W23d/W4l in MFMA B-frag layout (replaces readlane layouts).

#define BB   64
#define SS   100
#define DK   128
#define NTH  512

// ws dword offsets
#define OFF_PW1AB   0
#define OFF_PW23ABC 16384
#define OFF_PW4I    65536
#define OFF_PW5A    73728
#define OFF_PW23D   81920     // now: W23d B-frag layout, 16384 dwords
#define OFF_PW4L    98304     // now: W4l  B-frag layout,  8192 dwords
#define OFF_AFRAG   114688
#define OFF_S1      122880
#define OFF_AL      123008
#define OFF_PRE     532608
#define OFF_HTV     2171008   // 64*99*128 halves = 405504 dwords

typedef __attribute__((ext_vector_type(16))) float floatx16;
typedef __attribute__((ext_vector_type(8)))  short short8v;

__device__ __forceinline__ float frcp(float x) { return __builtin_amdgcn_rcpf(x); }
__device__ __forceinline__ float fsig(float x) { float t = __expf(-x); return frcp(1.0f + t); }
__device__ __forceinline__ float ftanh(float x) {
    x = fminf(20.0f, fmaxf(-20.0f, x));
    float t = __expf(-2.0f * x);
    return (1.0f - t) * frcp(1.0f + t);
}
__device__ __forceinline__ unsigned bfbits(float x) {
    unsigned u = __float_as_uint(x);
    return (u + 0x7fffu + ((u >> 16) & 1u)) >> 16;
}
__device__ __forceinline__ unsigned pack2(float a, float b) {
    return bfbits(a) | (bfbits(b) << 16);
}
__device__ __forceinline__ float blo(unsigned u) { return __uint_as_float(u << 16); }
__device__ __forceinline__ float bhi(unsigned u) { return __uint_as_float(u & 0xffff0000u); }

// lgkm-only workgroup barrier (R9-proven): no vmcnt drain across barriers.
__device__ __forceinline__ void wg_barrier() {
    asm volatile("s_waitcnt lgkmcnt(0)" ::: "memory");
    __builtin_amdgcn_s_barrier();
    asm volatile("" ::: "memory");
}

// ---- K0: weight packing ------------------------------------------------------
__global__ void k0_prep(const float* __restrict__ W1, const float* __restrict__ W2,
                        const float* __restrict__ W3, const float* __restrict__ W4,
                        const float* __restrict__ W5, unsigned* __restrict__ ws) {
    int g = blockIdx.x * blockDim.x + threadIdx.x;
    if (g < 16384) {
        int s = g >> 7, d = g & 127;
        ws[OFF_PW1AB + g] = pack2(W1[(2*s)*DK + d], W1[(2*s+1)*DK + d]);
    } else if (g < 65536) {
        int i = g - 16384; int s = i >> 8, j = i & 255;
        const float* M = (j < 128) ? W2 : W3; int jj = j & 127;
        ws[g] = pack2(M[(2*s)*DK + jj], M[(2*s+1)*DK + jj]);
    } else if (g < 73728) {
        int i = g - 65536; int s = i >> 7, j = i & 127;
        ws[g] = pack2(W4[(256+2*s)*DK + j], W4[(257+2*s)*DK + j]);
    } else if (g < 81920) {
        int i = g - 73728; int s = i >> 7, j = i & 127;
        ws[g] = pack2(W5[(2*s)*DK + j], W5[(2*s+1)*DK + j]);
    } else if (g < 98304) {
        // W23d in MFMA B-frag layout: idx = ((cw*8+kb)*64+lane)*4 + q
        // lane holds B[k = 16kb+8*(lane>>5)+{0..7}][j = 32cw+(lane&31)]
        int i = g - 81920;
        int q = i & 3, ln = (i >> 2) & 63, kb = (i >> 8) & 7, cw = i >> 11;
        int k = 16*kb + 8*(ln >> 5) + 2*q;
        int j = 32*cw + (ln & 31);
        const float* M = (j < 128) ? W2 : W3; int jj = j & 127;
        ws[g] = pack2(M[(384+k)*DK + jj], M[(385+k)*DK + jj]);
    } else if (g < 106496) {
        // W4l in MFMA B-frag layout: idx = ((cw*8+kb)*64+lane)*4 + q, cw 0..3
        int i = g - 98304;
        int q = i & 3, ln = (i >> 2) & 63, kb = (i >> 8) & 7, cw = i >> 11;
        int k = 16*kb + 8*(ln >> 5) + 2*q;
        int j = 32*cw + (ln & 31);
        ws[g] = pack2(W4[(128+k)*DK + j], W4[(129+k)*DK + j]);
    } else if (g < 114688) {
        // region unused (was PW5B; P6 moved to k4_y which reads W5 directly)
    } else if (g < 122880) {
        int i = g - 114688;
        int gg = i >> 11, kb = (i >> 8) & 7, ln = (i >> 2) & 63, c = i & 3;
        int m = ln & 31, hp = ln >> 5;
        int k0 = 16*kb + 8*hp + 2*c;
        ws[g] = pack2(W4[k0*DK + 32*gg + m], W4[(k0+1)*DK + 32*gg + m]);
    } else if (g < 123008) {
        int d = g - 122880;
        float z = 0.f;
        for (int k = 0; k < 128; k++) z += W1[(256+k)*DK + d];
        ws[g] = __float_as_uint(z);
    }
}

// ---- K1: AL (fp16), 4 timesteps per block ------------------------------------
__global__ __launch_bounds__(128)
void k1_al(const int* __restrict__ e_data, const int* __restrict__ a_data,
           const int* __restrict__ at_data, const float* __restrict__ Ee,
           const float* __restrict__ Eat, const float* __restrict__ b1,
           unsigned* __restrict__ ws) {
    const int b = blockIdx.x, t0 = 4 * blockIdx.y, tid = threadIdx.x;
    __shared__ __align__(16) float s_f[4][256];
    #pragma unroll
    for (int r = 0; r < 8; r++) {
        int id = r * 128 + tid; int i = id >> 8, k = id & 255;
        int t = t0 + i; float v = 0.f;
        if (t <= 98) {
            int e  = e_data[b*SS + t];
            int at = at_data[b*SS + t];
            v = (k < 128) ? Ee[(size_t)e*DK + k] : Eat[(size_t)at*DK + (k-128)];
        }
        s_f[i][k] = v;
    }
    __syncthreads();
    float s1v = __uint_as_float(ws[OFF_S1 + tid]);
    float b1v = b1[tid];
    float z[4];
    #pragma unroll
    for (int i = 0; i < 4; i++) z[i] = 0.f;
    #pragma unroll 2
    for (int s = 0; s < 128; s++) {
        unsigned w = ws[OFF_PW1AB + s*128 + tid];
        float wl = blo(w), wh = bhi(w);
        #pragma unroll
        for (int i = 0; i < 4; i++) {
            float2 f = *(const float2*)&s_f[i][2*s];
            z[i] += f.x*wl + f.y*wh;
        }
    }
    __half* AL = (__half*)(ws + OFF_AL);
    #pragma unroll
    for (int i = 0; i < 4; i++) {
        int t = t0 + i;
        if (t <= 98) {
            float a = (float)a_data[b*SS + t];
            AL[(size_t)(b*SS + t)*DK + tid] = __float2half(z[i] + a*s1v + b1v);
        }
    }
}

// ---- K2: PRE[b][t][512] (fp16), 4 timesteps per block ------------------------
__global__ __launch_bounds__(512)
void k2_pre(const int* __restrict__ e_data, const int* __restrict__ it_data,
            const float* __restrict__ Eit, const float* __restrict__ Ee,
            const float* __restrict__ b2, const float* __restrict__ b3,
            const float* __restrict__ b4, const float* __restrict__ b5,
            unsigned* __restrict__ ws) {
    const int b = blockIdx.x, t0 = 4 * blockIdx.y, tid = threadIdx.x;
    __shared__ __align__(16) float s_g[4][384];
    __shared__ __align__(16) float s_e[4][128];
    const __half* AL = (const __half*)(ws + OFF_AL);
    #pragma unroll
    for (int r = 0; r < 3; r++) {
        int id = r * 512 + tid; int i = id / 384; int k = id - 384*i;
        int t = t0 + i; float v = 0.f;
        if (t <= 98) {
            if (k < 128)      v = (t == 0) ? 0.f : (float)AL[(size_t)(b*SS + t - 1)*DK + k];
            else if (k < 256) v = Eit[(size_t)it_data[b*SS + t]*DK + (k - 128)];
            else              v = (float)AL[(size_t)(b*SS + t)*DK + (k - 256)];
        }
        s_g[i][k] = v;
    }
    {
        int id = tid; int i = id >> 7, k = id & 127;
        int t = t0 + i;
        s_e[i][k] = (t <= 98) ? Ee[(size_t)e_data[b*SS + t + 1]*DK + k] : 0.f;
    }
    __syncthreads();
    __half* PRE = (__half*)(ws + OFF_PRE);
    float z[4];
    #pragma unroll
    for (int i = 0; i < 4; i++) z[i] = 0.f;
    int col; float bb;
    if (tid < 256) {
        int j = tid;
        #pragma unroll 2
        for (int s = 0; s < 192; s++) {
            unsigned w = ws[OFF_PW23ABC + s*256 + j];
            float wl = blo(w), wh = bhi(w);
            #pragma unroll
            for (int i = 0; i < 4; i++) {
                float2 f = *(const float2*)&s_g[i][2*s];
                z[i] += f.x*wl + f.y*wh;
            }
        }
        col = j; bb = (j < 128) ? b2[j] : b3[j - 128];
    } else if (tid < 384) {
        int j = tid - 256;
        #pragma unroll 2
        for (int s = 0; s < 64; s++) {
            unsigned w = ws[OFF_PW4I + s*128 + j];
            float wl = blo(w), wh = bhi(w);
            #pragma unroll
            for (int i = 0; i < 4; i++) {
                float2 f = *(const float2*)&s_g[i][128 + 2*s];
                z[i] += f.x*wl + f.y*wh;
            }
        }
        col = 256 + j; bb = b4[j];
    } else {
        int j = tid - 384;
        #pragma unroll 2
        for (int s = 0; s < 64; s++) {
            unsigned w = ws[OFF_PW5A + s*128 + j];
            float wl = blo(w), wh = bhi(w);
            #pragma unroll
            for (int i = 0; i < 4; i++) {
                float2 f = *(const float2*)&s_e[i][2*s];
                z[i] += f.x*wl + f.y*wh;
            }
        }
        col = 384 + j; bb = b5[j];
    }
    #pragma unroll
    for (int i = 0; i < 4; i++) {
        int t = t0 + i;
        if (t <= 98) PRE[(size_t)(b*SS + t)*512 + col] = __float2half(z[i] + bb);
    }
}

// ---- K3: recurrent kernel ----------------------------------------------------
__global__ __launch_bounds__(NTH, 2)
void lpkt_kernel(const int* __restrict__ e_data, const float* __restrict__ qm,
                 const float* __restrict__ h0, unsigned* __restrict__ ws)
{
    const int b    = blockIdx.x;
    const int tid  = threadIdx.x;
    const int lane = tid & 63;
    const int w    = tid >> 6;
    const int g    = w & 3;            // MFMA d-block (h@W4h)
    const int hh   = w >> 2;           // cb pair {2hh, 2hh+1}; logit k-half
    const int h5   = lane >> 5;
    const int l31  = lane & 31;
    const int hf   = w >> 2;           // P3 k-half
    const int cw3  = w & 3;            // P3 col-block

    __shared__ __align__(16) unsigned s_frag[8192];      // 32 KB h B-fragments
    __shared__ __align__(16) float s_big[2 * 128 * 34];  // ht-reduce scratch
    __shared__ __align__(16) float s_pre[2][512];
    __shared__ __align__(16) float s_LG[128];
    __shared__ __align__(16) float s_h128[128];
    __shared__ __align__(16) float s_l128[2][128];
    __shared__ __align__(16) float s_red1[256];          // P1 output (full k)
    __shared__ __align__(16) float s_redE[256];          // P3 partials (2 k-halves)
    __shared__ __align__(16) unsigned s_htvb[64];        // htv packed bf16
    __shared__ __align__(16) float s_q[3][160];
    __shared__ int   s_ed[100];
    __shared__ float s_scal[1];

    // ---- permanent registers: afru 32 + pw23b 32 + pw4lb 16 + hreg 32 ---------
    uint4 afru[8], pw23b[8], pw4lb[4];
    float hreg[2][16];

    #pragma unroll
    for (int kb = 0; kb < 8; kb++)
        afru[kb] = ((const uint4*)(ws + OFF_AFRAG))[g*512 + kb*64 + lane];
    #pragma unroll
    for (int kb = 0; kb < 8; kb++)
        pw23b[kb] = ((const uint4*)(ws + OFF_PW23D))[(w*8 + kb)*64 + lane];
    #pragma unroll
    for (int kbl = 0; kbl < 4; kbl++)
        pw4lb[kbl] = ((const uint4*)(ws + OFF_PW4L))[((cw3*8 + hf*4 + kbl))*64 + lane];

    const __half* PRE = (const __half*)(ws + OFF_PRE);
    __half*       HTV = (__half*)(ws + OFF_HTV);

    // ---- prologue: staging + prefetch ----
    if (tid < 100) s_ed[tid] = e_data[b*SS + tid];
    if (tid < 160) { s_q[0][tid] = 0.f; s_q[1][tid] = 0.f; s_q[2][tid] = 0.f; }
    if (tid < 129) {
        s_q[0][tid] = qm[(size_t)e_data[b*SS + 0]*129 + tid];
        s_q[1][tid] = qm[(size_t)e_data[b*SS + 1]*129 + tid];
    }
    s_pre[0][tid] = __half2float(PRE[(size_t)(b*SS)*512 + tid]);
    float  q_pf   = (tid < 129) ? qm[(size_t)e_data[b*SS + 2]*129 + tid] : 0.f;
    __half pre_pf = PRE[(size_t)(b*SS + 1)*512 + tid];

    // ---- prologue: h0 -> regs + frags ----
    #pragma unroll
    for (int i = 0; i < 2; i++) {
        const int cb = 2*hh + i;
        const int n = 32*cb + l31;
        #pragma unroll
        for (int r = 0; r < 16; r++) {
            int d = 32*g + (r&3) + 8*(r>>2) + 4*h5;
            hreg[i][r] = h0[(size_t)n*DK + d];
        }
        #pragma unroll
        for (int q = 0; q < 4; q++) {
            int kb = 2*g + (q>>1);
            int lanep = l31 + ((q&1) << 5);
            int off = (((kb*4 + cb) << 10) + lanep*16 + (h5 << 3)) >> 2;
            uint2 pr = make_uint2(pack2(hreg[i][4*q],   hreg[i][4*q+1]),
                                  pack2(hreg[i][4*q+2], hreg[i][4*q+3]));
            *(uint2*)(s_frag + off) = pr;
        }
    }
    if (tid < 128) s_h128[tid] = h0[(size_t)128*DK + tid];
    __syncthreads();
    {   // vv0 -> s_big ; wave7: q0 sum
        if (w == 7) {
            float v = s_q[0][lane] + s_q[0][64+lane] + ((lane < 32) ? s_q[0][128+lane] : 0.f);
            #pragma unroll
            for (int m = 32; m > 0; m >>= 1) v += __shfl_xor(v, m);
            if (lane == 0) s_scal[0] = v;
        }
        float vv0[16];
        #pragma unroll
        for (int i = 0; i < 2; i++) {
            float qv = s_q[0][32*(2*hh + i) + l31];
            #pragma unroll
            for (int r = 0; r < 16; r++) {
                float p = qv * hreg[i][r];
                vv0[r] = i ? (vv0[r] + p) : p;
            }
        }
        #pragma unroll
        for (int r = 0; r < 16; r++) {
            int d = 32*g + (r&3) + 8*(r>>2) + 4*h5;
            s_big[(hh*128 + d)*34 + l31] = vv0[r];
        }
    }
    __syncthreads();
    if (tid < 128) {
        float a0 = 0.f, a1 = 0.f;
        #pragma unroll
        for (int jj = 0; jj < 16; jj++) {
            float2 x = *(const float2*)&s_big[tid*34 + 2*jj];
            float2 y = *(const float2*)&s_big[(128 + tid)*34 + 2*jj];
            a0 += x.x + x.y; a1 += y.x + y.y;
        }
        float htvv = (a0 + a1 + s_q[0][128]*s_h128[tid]) * frcp(s_scal[0]);
        float oth  = __shfl_xor(htvv, 1);
        if (!(tid & 1)) s_htvb[tid >> 1] = pack2(htvv, oth);
    }
    __syncthreads();

    // ---- recurrence: 4 lgkm-only barriers per step ----
    for (int t = 0; t < SS - 1; t++) {
        const int pbp = t & 1;
        const float* qc = s_q[t % 3];
        const float* qn = s_q[(t + 1) % 3];

        // ph0: stage prefetched rows; issue next prefetch; qsum(w7);
        //      P1 MFMA (htv.W23d); h@W4h MFMA; row-128 logit
        if (t + 2 <= 99 && tid < 129) s_q[(t + 2) % 3][tid] = q_pf;
        if (t + 1 <= 98)              s_pre[1 - pbp][tid] = __half2float(pre_pf);
        if (t + 3 <= 99 && tid < 129) q_pf  = qm[(size_t)s_ed[t + 3]*129 + tid];
        if (t + 2 <= 98)              pre_pf = PRE[(size_t)(b*SS + t + 2)*512 + tid];
        if (w == 7) {
            float v = qn[lane] + qn[64 + lane] + ((lane < 32) ? qn[128 + lane] : 0.f);
            #pragma unroll
            for (int m = 32; m > 0; m >>= 1) v += __shfl_xor(v, m);
            if (lane == 0) s_scal[0] = v;
        }
        // P1: out col j = 32w + l31 (row 0 -> reg 0, h5==0 lanes)
        {
            floatx16 p1 = (floatx16)(0.f);
            #pragma unroll
            for (int kb = 0; kb < 8; kb++) {
                uint4 a1 = *(const uint4*)&s_htvb[kb*8 + 4*h5];
                p1 = __builtin_amdgcn_mfma_f32_32x32x16_bf16(
                        __builtin_bit_cast(short8v, a1),
                        __builtin_bit_cast(short8v, pw23b[kb]), p1, 0, 0, 0);
            }
            if (h5 == 0) s_red1[w*32 + l31] = p1[0];
        }
        // h@W4h (inputs: prev-step s_frag, stable since BD/BE)
        floatx16 am[2];
        #pragma unroll
        for (int i = 0; i < 2; i++) {
            const int cb = 2*hh + i;
            floatx16 a = (floatx16)(0.f);
            #pragma unroll
            for (int kb = 0; kb < 8; kb++) {
                short8v bf = *(const short8v*)((const char*)s_frag +
                               (((kb*4 + cb) << 10) + lane*16));
                a = __builtin_amdgcn_mfma_f32_32x32x16_bf16(
                        __builtin_bit_cast(short8v, afru[kb]), bf, a, 0, 0, 0);
            }
            am[i] = a;
        }
        // row-128 logit, split across hh halves
        {
            float part = 0.f;
            #pragma unroll
            for (int kbl = 0; kbl < 4; kbl++) {
                const int kb = 4*hh + kbl;
                const int kb0 = 16*kb + 8*h5;
                uint4 u = afru[kb];
                part += s_h128[kb0+0]*blo(u.x) + s_h128[kb0+1]*bhi(u.x);
                part += s_h128[kb0+2]*blo(u.y) + s_h128[kb0+3]*bhi(u.y);
                part += s_h128[kb0+4]*blo(u.z) + s_h128[kb0+5]*bhi(u.z);
                part += s_h128[kb0+6]*blo(u.w) + s_h128[kb0+7]*bhi(u.w);
            }
            part += __shfl_xor(part, 32);
            if (h5 == 0) s_l128[hh][32*g + l31] = part;
        }
        wg_barrier();   // BA
        // ph23: per-lane LG (m = 64*hf + lane) + in-wave A-frag pack + P3 MFMA
        {
            const int m = 64*hf + lane;
            float z2v = s_red1[m]       + s_pre[pbp][m];
            float z3v = s_red1[128 + m] + s_pre[pbp][128 + m];
            float LGv = fsig(z3v) * (ftanh(z2v) + 1.f) * 0.5f;
            if (cw3 == 0) s_LG[m] = LGv;
            // pair-pack: lanes 2i,2i+1 both hold pack2(LG[64hf+2i], LG[64hf+2i+1])
            float oth = __shfl_xor(LGv, 1);
            float lo  = (lane & 1) ? oth : LGv;
            float hi  = (lane & 1) ? LGv : oth;
            int   pk  = (int)pack2(lo, hi);
            floatx16 p3 = (floatx16)(0.f);
            #pragma unroll
            for (int kbl = 0; kbl < 4; kbl++) {
                const int p0 = 8*kbl + 4*h5;
                uint4 a3;
                a3.x = (unsigned)__builtin_amdgcn_ds_bpermute(8*(p0+0), pk);
                a3.y = (unsigned)__builtin_amdgcn_ds_bpermute(8*(p0+1), pk);
                a3.z = (unsigned)__builtin_amdgcn_ds_bpermute(8*(p0+2), pk);
                a3.w = (unsigned)__builtin_amdgcn_ds_bpermute(8*(p0+3), pk);
                p3 = __builtin_amdgcn_mfma_f32_32x32x16_bf16(
                        __builtin_bit_cast(short8v, a3),
                        __builtin_bit_cast(short8v, pw4lb[kbl]), p3, 0, 0, 0);
            }
            if (h5 == 0) s_redE[hf*128 + 32*cw3 + l31] = p3[0];
        }
        wg_barrier();   // BB
        // ph5: gates + h update + vv + frag rewrite + scatter + row-128 update
        {
            float lgv[16], cvv[16], vv[16];
            const float4* LG4 = (const float4*)s_LG;
            const float4* RE4 = (const float4*)s_redE;
            const float4* PR4 = (const float4*)s_pre[pbp];
            #pragma unroll
            for (int u = 0; u < 4; u++) {
                const int idx = 8*g + 2*u + h5;
                float4 lg = LG4[idx];
                float4 c0 = RE4[idx];
                float4 c1 = RE4[32 + idx];
                float4 pv = PR4[64 + idx];
                lgv[4*u+0]=lg.x; lgv[4*u+1]=lg.y; lgv[4*u+2]=lg.z; lgv[4*u+3]=lg.w;
                cvv[4*u+0]=c0.x+c1.x+pv.x; cvv[4*u+1]=c0.y+c1.y+pv.y;
                cvv[4*u+2]=c0.z+c1.z+pv.z; cvv[4*u+3]=c0.w+c1.w+pv.w;
            }
            #pragma unroll
            for (int i = 0; i < 2; i++) {
                const int cb = 2*hh + i;
                const int n = 32*cb + l31;
                const float qcv = qc[n], qnv = qn[n];
                #pragma unroll
                for (int r = 0; r < 16; r++) {
                    float gg = fsig(am[i][r] + cvv[r]);
                    float hn = qcv*lgv[r] + gg*hreg[i][r];
                    hreg[i][r] = hn;
                    float p = qnv*hn;
                    vv[r] = i ? (vv[r] + p) : p;
                }
            }
            #pragma unroll
            for (int i = 0; i < 2; i++) {
                const int cb = 2*hh + i;
                #pragma unroll
                for (int q = 0; q < 4; q++) {
                    int kb = 2*g + (q>>1);
                    int lanep = l31 + ((q&1) << 5);
                    int off = (((kb*4 + cb) << 10) + lanep*16 + (h5 << 3)) >> 2;
                    uint2 pr = make_uint2(pack2(hreg[i][4*q],   hreg[i][4*q+1]),
                                          pack2(hreg[i][4*q+2], hreg[i][4*q+3]));
                    *(uint2*)(s_frag + off) = pr;
                }
            }
            #pragma unroll
            for (int r = 0; r < 16; r++) {
                int d = 32*g + (r&3) + 8*(r>>2) + 4*h5;
                s_big[(hh*128 + d)*34 + l31] = vv[r];
            }
            if (tid < 128) {
                float c128 = s_redE[tid] + s_redE[128 + tid] + s_pre[pbp][256 + tid];
                float gg = fsig(s_l128[0][tid] + s_l128[1][tid] + c128);
                s_h128[tid] = qc[128]*s_LG[tid] + gg*s_h128[tid];
            }
        }
        wg_barrier();   // BD
        // ph7: h_tilde reduce -> packed bf16 LDS + fp16 HTV history store
        if (tid < 128) {
            float a0 = 0.f, a1 = 0.f;
            #pragma unroll
            for (int jj = 0; jj < 16; jj++) {
                float2 x = *(const float2*)&s_big[tid*34 + 2*jj];
                float2 y = *(const float2*)&s_big[(128 + tid)*34 + 2*jj];
                a0 += x.x + x.y; a1 += y.x + y.y;
            }
            float htvv = (a0 + a1 + qn[128]*s_h128[tid]) * frcp(s_scal[0]);
            HTV[((size_t)b*(SS-1) + t)*128 + tid] = __float2half(htvv);
            float oth = __shfl_xor(htvv, 1);
            if (!(tid & 1)) s_htvb[tid >> 1] = pack2(htvv, oth);
        }
        wg_barrier();   // BE
    }
}

// ---- K4: y epilogue (parallel over all b,t) ----------------------------------
__global__ __launch_bounds__(128)
void k4_y(const float* __restrict__ W5, float* __restrict__ out,
          const unsigned* __restrict__ ws) {
    const int b = blockIdx.x, t = blockIdx.y, j = threadIdx.x;
    const __half* HTV = (const __half*)(ws + OFF_HTV);
    const __half* PRE = (const __half*)(ws + OFF_PRE);
    __shared__ float s_h[128];
    __shared__ float s_p[2];
    s_h[j] = __half2float(HTV[((size_t)b*(SS-1) + t)*128 + j]);
    __syncthreads();
    float z = __half2float(PRE[(size_t)(b*SS + t)*512 + 384 + j]);
    #pragma unroll 4
    for (int k = 0; k < 128; k++) z += s_h[k] * W5[(size_t)(128 + k)*DK + j];
    float v = fsig(z);
    #pragma unroll
    for (int m = 32; m > 0; m >>= 1) v += __shfl_xor(v, m);
    if ((j & 63) == 0) s_p[j >> 6] = v;
    __syncthreads();
    if (j == 0) {
        out[b*SS + t + 1] = (s_p[0] + s_p[1]) * (1.0f / 128.0f);
        if (t == 0) out[b*SS] = 0.f;
    }
}

extern "C" void kernel_launch(void* const* d_in, const int* in_sizes, int n_in,
                              void* d_out, int out_size, void* d_ws, size_t ws_size,
                              hipStream_t stream) {
    const int*   e_data  = (const int*)d_in[0];
    const int*   a_data  = (const int*)d_in[1];
    const int*   it_data = (const int*)d_in[2];
    const int*   at_data = (const int*)d_in[3];
    const float* qm  = (const float*)d_in[4];
    const float* h0  = (const float*)d_in[5];
    const float* Ee  = (const float*)d_in[6];
    const float* Eat = (const float*)d_in[7];
    const float* Eit = (const float*)d_in[8];
    const float* W1  = (const float*)d_in[9];
    const float* b1  = (const float*)d_in[10];
    const float* W2  = (const float*)d_in[11];
    const float* b2  = (const float*)d_in[12];
    const float* W3  = (const float*)d_in[13];
    const float* b3  = (const float*)d_in[14];
    const float* W4  = (const float*)d_in[15];
    const float* b4  = (const float*)d_in[16];
    const float* W5  = (const float*)d_in[17];
    const float* b5  = (const float*)d_in[18];
    float* out = (float*)d_out;
    unsigned* ws = (unsigned*)d_ws;

    k0_prep<<<dim3((123008 + 255) / 256), dim3(256), 0, stream>>>(W1, W2, W3, W4, W5, ws);
    k1_al<<<dim3(BB, 25), dim3(128), 0, stream>>>(e_data, a_data, at_data, Ee, Eat, b1, ws);
    k2_pre<<<dim3(BB, 25), dim3(512), 0, stream>>>(e_data, it_data, Eit, Ee, b2, b3, b4, b5, ws);
    lpkt_kernel<<<dim3(BB), dim3(NTH), 0, stream>>>(e_data, qm, h0, ws);
    k4_y<<<dim3(BB, SS - 1), dim3(128), 0, stream>>>(W5, out, ws);
}

// Round 4
// 644.691 us; speedup vs baseline: 1.4623x; 1.0497x over previous
//
#include <hip/hip_runtime.h>
#include <hip/hip_fp16.h>
#include <math.h>

// LPKT R12 = R11 de-risked. Same structure as R11 (4 lgkm-only barriers,
// rebalanced phases), with the unverified VOP3P inline asm removed:
// - v_cvt_pk_bf16_f32 (guide-verified asm) for all hot bf16 packs.
// - Gate math on ext_vector float2: clang contracts to v_pk_* where available,
//   falls back to scalar otherwise (never worse than R10).
// - __builtin_amdgcn_exp2f instead of v_exp_f32 asm.
// Step chain: BE -> stage+P1 -> BA -> LG+P3 -> BB -> gates -> BD ->
//             (htv reduce || am(t+1) MFMA + logit(t+1) + qsum(t+2)) -> BE.

#define BB   64
#define SS   100
#define DK   128
#define NTH  512

// ws dword offsets
#define OFF_PW1AB   0
#define OFF_PW23ABC 16384
#define OFF_PW4I    65536
#define OFF_PW5A    73728
#define OFF_PW23D   81920     // W23d B-frag layout, 16384 dwords
#define OFF_PW4L    98304     // W4l  B-frag layout,  8192 dwords
#define OFF_AFRAG   114688
#define OFF_S1      122880
#define OFF_AL      123008
#define OFF_PRE     532608
#define OFF_HTV     2171008   // 64*99*128 halves = 405504 dwords

typedef __attribute__((ext_vector_type(16))) float floatx16;
typedef __attribute__((ext_vector_type(8)))  short short8v;
typedef __attribute__((ext_vector_type(2)))  float floatx2;

__device__ __forceinline__ float frcp(float x) { return __builtin_amdgcn_rcpf(x); }
__device__ __forceinline__ float fsig(float x) { float t = __expf(-x); return frcp(1.0f + t); }
__device__ __forceinline__ float ftanh(float x) {
    x = fminf(20.0f, fmaxf(-20.0f, x));
    float t = __expf(-2.0f * x);
    return (1.0f - t) * frcp(1.0f + t);
}
__device__ __forceinline__ unsigned bfbits(float x) {
    unsigned u = __float_as_uint(x);
    return (u + 0x7fffu + ((u >> 16) & 1u)) >> 16;
}
__device__ __forceinline__ unsigned pack2(float a, float b) {
    return bfbits(a) | (bfbits(b) << 16);
}
__device__ __forceinline__ float blo(unsigned u) { return __uint_as_float(u << 16); }
__device__ __forceinline__ float bhi(unsigned u) { return __uint_as_float(u & 0xffff0000u); }

// single-instruction RNE bf16 pair pack (gfx950; guide-verified syntax)
__device__ __forceinline__ unsigned cvtpk(float a, float b) {
    unsigned r;
    asm("v_cvt_pk_bf16_f32 %0, %1, %2" : "=v"(r) : "v"(a), "v"(b));
    return r;
}

// lgkm-only workgroup barrier (R9-proven): no vmcnt drain across barriers.
__device__ __forceinline__ void wg_barrier() {
    asm volatile("s_waitcnt lgkmcnt(0)" ::: "memory");
    __builtin_amdgcn_s_barrier();
    asm volatile("" ::: "memory");
}

// ---- K0: weight packing (unchanged from R10) ---------------------------------
__global__ void k0_prep(const float* __restrict__ W1, const float* __restrict__ W2,
                        const float* __restrict__ W3, const float* __restrict__ W4,
                        const float* __restrict__ W5, unsigned* __restrict__ ws) {
    int g = blockIdx.x * blockDim.x + threadIdx.x;
    if (g < 16384) {
        int s = g >> 7, d = g & 127;
        ws[OFF_PW1AB + g] = pack2(W1[(2*s)*DK + d], W1[(2*s+1)*DK + d]);
    } else if (g < 65536) {
        int i = g - 16384; int s = i >> 8, j = i & 255;
        const float* M = (j < 128) ? W2 : W3; int jj = j & 127;
        ws[g] = pack2(M[(2*s)*DK + jj], M[(2*s+1)*DK + jj]);
    } else if (g < 73728) {
        int i = g - 65536; int s = i >> 7, j = i & 127;
        ws[g] = pack2(W4[(256+2*s)*DK + j], W4[(257+2*s)*DK + j]);
    } else if (g < 81920) {
        int i = g - 73728; int s = i >> 7, j = i & 127;
        ws[g] = pack2(W5[(2*s)*DK + j], W5[(2*s+1)*DK + j]);
    } else if (g < 98304) {
        // W23d B-frag: lane holds B[k=16kb+8(ln>>5)+2q+{0,1}][j=32cw+(ln&31)]
        int i = g - 81920;
        int q = i & 3, ln = (i >> 2) & 63, kb = (i >> 8) & 7, cw = i >> 11;
        int k = 16*kb + 8*(ln >> 5) + 2*q;
        int j = 32*cw + (ln & 31);
        const float* M = (j < 128) ? W2 : W3; int jj = j & 127;
        ws[g] = pack2(M[(384+k)*DK + jj], M[(385+k)*DK + jj]);
    } else if (g < 106496) {
        // W4l B-frag, cw 0..3
        int i = g - 98304;
        int q = i & 3, ln = (i >> 2) & 63, kb = (i >> 8) & 7, cw = i >> 11;
        int k = 16*kb + 8*(ln >> 5) + 2*q;
        int j = 32*cw + (ln & 31);
        ws[g] = pack2(W4[(128+k)*DK + j], W4[(129+k)*DK + j]);
    } else if (g < 114688) {
        // unused
    } else if (g < 122880) {
        int i = g - 114688;
        int gg = i >> 11, kb = (i >> 8) & 7, ln = (i >> 2) & 63, c = i & 3;
        int m = ln & 31, hp = ln >> 5;
        int k0 = 16*kb + 8*hp + 2*c;
        ws[g] = pack2(W4[k0*DK + 32*gg + m], W4[(k0+1)*DK + 32*gg + m]);
    } else if (g < 123008) {
        int d = g - 122880;
        float z = 0.f;
        for (int k = 0; k < 128; k++) z += W1[(256+k)*DK + d];
        ws[g] = __float_as_uint(z);
    }
}

// ---- K1: AL (fp16), 4 timesteps per block ------------------------------------
__global__ __launch_bounds__(128)
void k1_al(const int* __restrict__ e_data, const int* __restrict__ a_data,
           const int* __restrict__ at_data, const float* __restrict__ Ee,
           const float* __restrict__ Eat, const float* __restrict__ b1,
           unsigned* __restrict__ ws) {
    const int b = blockIdx.x, t0 = 4 * blockIdx.y, tid = threadIdx.x;
    __shared__ __align__(16) float s_f[4][256];
    #pragma unroll
    for (int r = 0; r < 8; r++) {
        int id = r * 128 + tid; int i = id >> 8, k = id & 255;
        int t = t0 + i; float v = 0.f;
        if (t <= 98) {
            int e  = e_data[b*SS + t];
            int at = at_data[b*SS + t];
            v = (k < 128) ? Ee[(size_t)e*DK + k] : Eat[(size_t)at*DK + (k-128)];
        }
        s_f[i][k] = v;
    }
    __syncthreads();
    float s1v = __uint_as_float(ws[OFF_S1 + tid]);
    float b1v = b1[tid];
    float z[4];
    #pragma unroll
    for (int i = 0; i < 4; i++) z[i] = 0.f;
    #pragma unroll 2
    for (int s = 0; s < 128; s++) {
        unsigned w = ws[OFF_PW1AB + s*128 + tid];
        float wl = blo(w), wh = bhi(w);
        #pragma unroll
        for (int i = 0; i < 4; i++) {
            float2 f = *(const float2*)&s_f[i][2*s];
            z[i] += f.x*wl + f.y*wh;
        }
    }
    __half* AL = (__half*)(ws + OFF_AL);
    #pragma unroll
    for (int i = 0; i < 4; i++) {
        int t = t0 + i;
        if (t <= 98) {
            float a = (float)a_data[b*SS + t];
            AL[(size_t)(b*SS + t)*DK + tid] = __float2half(z[i] + a*s1v + b1v);
        }
    }
}

// ---- K2: PRE[b][t][512] (fp16), 4 timesteps per block ------------------------
__global__ __launch_bounds__(512)
void k2_pre(const int* __restrict__ e_data, const int* __restrict__ it_data,
            const float* __restrict__ Eit, const float* __restrict__ Ee,
            const float* __restrict__ b2, const float* __restrict__ b3,
            const float* __restrict__ b4, const float* __restrict__ b5,
            unsigned* __restrict__ ws) {
    const int b = blockIdx.x, t0 = 4 * blockIdx.y, tid = threadIdx.x;
    __shared__ __align__(16) float s_g[4][384];
    __shared__ __align__(16) float s_e[4][128];
    const __half* AL = (const __half*)(ws + OFF_AL);
    #pragma unroll
    for (int r = 0; r < 3; r++) {
        int id = r * 512 + tid; int i = id / 384; int k = id - 384*i;
        int t = t0 + i; float v = 0.f;
        if (t <= 98) {
            if (k < 128)      v = (t == 0) ? 0.f : (float)AL[(size_t)(b*SS + t - 1)*DK + k];
            else if (k < 256) v = Eit[(size_t)it_data[b*SS + t]*DK + (k - 128)];
            else              v = (float)AL[(size_t)(b*SS + t)*DK + (k - 256)];
        }
        s_g[i][k] = v;
    }
    {
        int id = tid; int i = id >> 7, k = id & 127;
        int t = t0 + i;
        s_e[i][k] = (t <= 98) ? Ee[(size_t)e_data[b*SS + t + 1]*DK + k] : 0.f;
    }
    __syncthreads();
    __half* PRE = (__half*)(ws + OFF_PRE);
    float z[4];
    #pragma unroll
    for (int i = 0; i < 4; i++) z[i] = 0.f;
    int col; float bb;
    if (tid < 256) {
        int j = tid;
        #pragma unroll 2
        for (int s = 0; s < 192; s++) {
            unsigned w = ws[OFF_PW23ABC + s*256 + j];
            float wl = blo(w), wh = bhi(w);
            #pragma unroll
            for (int i = 0; i < 4; i++) {
                float2 f = *(const float2*)&s_g[i][2*s];
                z[i] += f.x*wl + f.y*wh;
            }
        }
        col = j; bb = (j < 128) ? b2[j] : b3[j - 128];
    } else if (tid < 384) {
        int j = tid - 256;
        #pragma unroll 2
        for (int s = 0; s < 64; s++) {
            unsigned w = ws[OFF_PW4I + s*128 + j];
            float wl = blo(w), wh = bhi(w);
            #pragma unroll
            for (int i = 0; i < 4; i++) {
                float2 f = *(const float2*)&s_g[i][128 + 2*s];
                z[i] += f.x*wl + f.y*wh;
            }
        }
        col = 256 + j; bb = b4[j];
    } else {
        int j = tid - 384;
        #pragma unroll 2
        for (int s = 0; s < 64; s++) {
            unsigned w = ws[OFF_PW5A + s*128 + j];
            float wl = blo(w), wh = bhi(w);
            #pragma unroll
            for (int i = 0; i < 4; i++) {
                float2 f = *(const float2*)&s_e[i][2*s];
                z[i] += f.x*wl + f.y*wh;
            }
        }
        col = 384 + j; bb = b5[j];
    }
    #pragma unroll
    for (int i = 0; i < 4; i++) {
        int t = t0 + i;
        if (t <= 98) PRE[(size_t)(b*SS + t)*512 + col] = __float2half(z[i] + bb);
    }
}

// ---- K3: recurrent kernel ----------------------------------------------------
__global__ __launch_bounds__(NTH, 2)
void lpkt_kernel(const int* __restrict__ e_data, const float* __restrict__ qm,
                 const float* __restrict__ h0, unsigned* __restrict__ ws)
{
    const int b    = blockIdx.x;
    const int tid  = threadIdx.x;
    const int lane = tid & 63;
    const int w    = tid >> 6;
    const int g    = w & 3;            // MFMA d-block (h@W4h)
    const int hh   = w >> 2;           // cb pair {2hh, 2hh+1}; logit k-half
    const int h5   = lane >> 5;
    const int l31  = lane & 31;
    const int hf   = w >> 2;           // P3 k-half
    const int cw3  = w & 3;            // P3 col-block

    __shared__ __align__(16) unsigned s_frag[8192];      // 32 KB h B-fragments
    __shared__ __align__(16) float s_big[2 * 128 * 34];  // ht-reduce scratch
    __shared__ __align__(16) float s_pre[2][512];
    __shared__ __align__(16) float s_LG[128];
    __shared__ __align__(16) float s_h128[128];
    __shared__ __align__(16) float s_l128[2][128];
    __shared__ __align__(16) float s_red1[256];          // P1 output
    __shared__ __align__(16) float s_redE[256];          // P3 partials
    __shared__ __align__(16) unsigned s_htvb[64];        // htv packed bf16
    __shared__ __align__(16) float s_q[3][160];
    __shared__ int   s_ed[100];
    __shared__ float s_scal[2];                          // sum(q[k]) in slot k&1

    // ---- permanent registers ----
    uint4    afru[8], pw23b[8], pw4lb[4];
    floatx2  hreg2[2][8];
    floatx16 am[2];

    #pragma unroll
    for (int kb = 0; kb < 8; kb++)
        afru[kb] = ((const uint4*)(ws + OFF_AFRAG))[g*512 + kb*64 + lane];
    #pragma unroll
    for (int kb = 0; kb < 8; kb++)
        pw23b[kb] = ((const uint4*)(ws + OFF_PW23D))[(w*8 + kb)*64 + lane];
    #pragma unroll
    for (int kbl = 0; kbl < 4; kbl++)
        pw4lb[kbl] = ((const uint4*)(ws + OFF_PW4L))[((cw3*8 + hf*4 + kbl))*64 + lane];

    const __half* PRE = (const __half*)(ws + OFF_PRE);
    __half*       HTV = (__half*)(ws + OFF_HTV);

    // ---- prologue phase 1: staging + prefetch + h0 -> regs/frags ----
    if (tid < 100) s_ed[tid] = e_data[b*SS + tid];
    if (tid < 160) { s_q[0][tid] = 0.f; s_q[1][tid] = 0.f; s_q[2][tid] = 0.f; }
    if (tid < 129) {
        s_q[0][tid] = qm[(size_t)e_data[b*SS + 0]*129 + tid];
        s_q[1][tid] = qm[(size_t)e_data[b*SS + 1]*129 + tid];
    }
    s_pre[0][tid] = __half2float(PRE[(size_t)(b*SS)*512 + tid]);
    float  q_pf   = (tid < 129) ? qm[(size_t)e_data[b*SS + 2]*129 + tid] : 0.f;
    __half pre_pf = PRE[(size_t)(b*SS + 1)*512 + tid];

    #pragma unroll
    for (int i = 0; i < 2; i++) {
        const int cb = 2*hh + i;
        const int n = 32*cb + l31;
        #pragma unroll
        for (int m = 0; m < 8; m++) {
            int r = 2*m;
            int d = 32*g + (r&3) + 8*(r>>2) + 4*h5;
            hreg2[i][m] = *(const floatx2*)&h0[(size_t)n*DK + d];
        }
        #pragma unroll
        for (int q = 0; q < 4; q++) {
            int kb = 2*g + (q>>1);
            int lanep = l31 + ((q&1) << 5);
            int off = (((kb*4 + cb) << 10) + lanep*16 + (h5 << 3)) >> 2;
            uint2 pr = make_uint2(cvtpk(hreg2[i][2*q].x,   hreg2[i][2*q].y),
                                  cvtpk(hreg2[i][2*q+1].x, hreg2[i][2*q+1].y));
            *(uint2*)(s_frag + off) = pr;
        }
    }
    if (tid < 128) s_h128[tid] = h0[(size_t)128*DK + tid];
    __syncthreads();

    // ---- prologue phase 2: vv0 scatter + q0/q1 sums + am(0) + logit(0) ----
    {
        if (w == 7) {
            float v0 = s_q[0][lane] + s_q[0][64+lane] + ((lane < 32) ? s_q[0][128+lane] : 0.f);
            float v1 = s_q[1][lane] + s_q[1][64+lane] + ((lane < 32) ? s_q[1][128+lane] : 0.f);
            #pragma unroll
            for (int m = 32; m > 0; m >>= 1) { v0 += __shfl_xor(v0, m); v1 += __shfl_xor(v1, m); }
            if (lane == 0) { s_scal[0] = v0; s_scal[1] = v1; }
        }
        floatx2 vv0[8];
        #pragma unroll
        for (int i = 0; i < 2; i++) {
            float qv = s_q[0][32*(2*hh + i) + l31];
            floatx2 qv2 = {qv, qv};
            #pragma unroll
            for (int m = 0; m < 8; m++) {
                if (i == 0) vv0[m] = qv2 * hreg2[i][m];
                else        vv0[m] = vv0[m] + qv2 * hreg2[i][m];
            }
        }
        #pragma unroll
        for (int m = 0; m < 8; m++) {
            int r = 2*m;
            int d = 32*g + (r&3) + 8*(r>>2) + 4*h5;
            s_big[(hh*128 + d)*34 + l31]       = vv0[m].x;
            s_big[(hh*128 + d + 1)*34 + l31]   = vv0[m].y;
        }
        // am(0) + logit(0)
        #pragma unroll
        for (int i = 0; i < 2; i++) {
            const int cb = 2*hh + i;
            floatx16 a = (floatx16)(0.f);
            #pragma unroll
            for (int kb = 0; kb < 8; kb++) {
                short8v bf = *(const short8v*)((const char*)s_frag +
                               (((kb*4 + cb) << 10) + lane*16));
                a = __builtin_amdgcn_mfma_f32_32x32x16_bf16(
                        __builtin_bit_cast(short8v, afru[kb]), bf, a, 0, 0, 0);
            }
            am[i] = a;
        }
        {
            float part = 0.f;
            #pragma unroll
            for (int kbl = 0; kbl < 4; kbl++) {
                const int kb = 4*hh + kbl;
                const int kb0 = 16*kb + 8*h5;
                uint4 u = afru[kb];
                part += s_h128[kb0+0]*blo(u.x) + s_h128[kb0+1]*bhi(u.x);
                part += s_h128[kb0+2]*blo(u.y) + s_h128[kb0+3]*bhi(u.y);
                part += s_h128[kb0+4]*blo(u.z) + s_h128[kb0+5]*bhi(u.z);
                part += s_h128[kb0+6]*blo(u.w) + s_h128[kb0+7]*bhi(u.w);
            }
            part += __shfl_xor(part, 32);
            if (h5 == 0) s_l128[hh][32*g + l31] = part;
        }
    }
    __syncthreads();

    // ---- prologue phase 3: htv0 (8-wave balanced reduce) -> s_htvb ----
    {
        const int row = 16*w + (lane >> 2);
        const int qr  = lane & 3;
        const float* basep = &s_big[(((qr >> 1) << 7) + row)*34 + ((qr & 1) << 4)];
        floatx2 a2 = {0.f, 0.f};
        #pragma unroll
        for (int jj = 0; jj < 8; jj++)
            a2 = a2 + *(const floatx2*)(basep + 2*jj);
        float a0 = a2.x + a2.y;
        a0 += __shfl_xor(a0, 1);
        a0 += __shfl_xor(a0, 2);
        float htvv = (a0 + s_q[0][128]*s_h128[row]) * frcp(s_scal[0]);
        float oth = __shfl_down(htvv, 4);
        if ((lane & 7) == 0) s_htvb[row >> 1] = cvtpk(htvv, oth);
    }
    __syncthreads();

    // ---- recurrence: 4 lgkm-only barriers per step ----
    for (int t = 0; t < SS - 1; t++) {
        const int pbp = t & 1;
        const float* qc = s_q[t % 3];
        const float* qn = s_q[(t + 1) % 3];

        // ---- phY: staging + prefetch + P1 MFMA ----
        if (t + 2 <= 99 && tid < 129) s_q[(t + 2) % 3][tid] = q_pf;
        if (t + 1 <= 98)              s_pre[1 - pbp][tid] = __half2float(pre_pf);
        if (t + 3 <= 99 && tid < 129) q_pf  = qm[(size_t)s_ed[t + 3]*129 + tid];
        if (t + 2 <= 98)              pre_pf = PRE[(size_t)(b*SS + t + 2)*512 + tid];
        {
            floatx16 p1 = (floatx16)(0.f);
            #pragma unroll
            for (int kb = 0; kb < 8; kb++) {
                uint4 a1 = *(const uint4*)&s_htvb[kb*8 + 4*h5];
                p1 = __builtin_amdgcn_mfma_f32_32x32x16_bf16(
                        __builtin_bit_cast(short8v, a1),
                        __builtin_bit_cast(short8v, pw23b[kb]), p1, 0, 0, 0);
            }
            if (h5 == 0) s_red1[w*32 + l31] = p1[0];
        }
        wg_barrier();   // BA
        // ---- ph23: per-lane LG + in-wave A-frag pack + P3 MFMA ----
        {
            const int m = 64*hf + lane;
            float z2v = s_red1[m]       + s_pre[pbp][m];
            float z3v = s_red1[128 + m] + s_pre[pbp][128 + m];
            float LGv = fsig(z3v) * (ftanh(z2v) + 1.f) * 0.5f;
            if (cw3 == 0) s_LG[m] = LGv;
            float oth = __shfl_xor(LGv, 1);
            float lo  = (lane & 1) ? oth : LGv;
            float hi  = (lane & 1) ? LGv : oth;
            int   pk  = (int)cvtpk(lo, hi);
            floatx16 p3 = (floatx16)(0.f);
            #pragma unroll
            for (int kbl = 0; kbl < 4; kbl++) {
                const int p0 = 8*kbl + 4*h5;
                uint4 a3;
                a3.x = (unsigned)__builtin_amdgcn_ds_bpermute(8*(p0+0), pk);
                a3.y = (unsigned)__builtin_amdgcn_ds_bpermute(8*(p0+1), pk);
                a3.z = (unsigned)__builtin_amdgcn_ds_bpermute(8*(p0+2), pk);
                a3.w = (unsigned)__builtin_amdgcn_ds_bpermute(8*(p0+3), pk);
                p3 = __builtin_amdgcn_mfma_f32_32x32x16_bf16(
                        __builtin_bit_cast(short8v, a3),
                        __builtin_bit_cast(short8v, pw4lb[kbl]), p3, 0, 0, 0);
            }
            if (h5 == 0) s_redE[hf*128 + 32*cw3 + l31] = p3[0];
        }
        wg_barrier();   // BB
        // ---- ph5: gates (float2 vector math) + frag rewrite + vv scatter + h128 ----
        {
            floatx2 lg2[8], cv2[8], vv2[8];
            const float4* LG4 = (const float4*)s_LG;
            const float4* RE4 = (const float4*)s_redE;
            const float4* PR4 = (const float4*)s_pre[pbp];
            #pragma unroll
            for (int u = 0; u < 4; u++) {
                const int idx = 8*g + 2*u + h5;
                float4 lg = LG4[idx];
                float4 c0 = RE4[idx];
                float4 c1 = RE4[32 + idx];
                float4 pv = PR4[64 + idx];
                lg2[2*u]   = floatx2{lg.x, lg.y};
                lg2[2*u+1] = floatx2{lg.z, lg.w};
                cv2[2*u]   = floatx2{c0.x, c0.y} + floatx2{c1.x, c1.y} + floatx2{pv.x, pv.y};
                cv2[2*u+1] = floatx2{c0.z, c0.w} + floatx2{c1.z, c1.w} + floatx2{pv.z, pv.w};
            }
            const floatx2 nl2e2 = {-1.442695041f, -1.442695041f};
            #pragma unroll
            for (int i = 0; i < 2; i++) {
                const int cb = 2*hh + i;
                const int n = 32*cb + l31;
                const float qcv = qc[n], qnv = qn[n];
                const floatx2 qc2 = {qcv, qcv};
                const floatx2 qn2 = {qnv, qnv};
                #pragma unroll
                for (int m = 0; m < 8; m++) {
                    floatx2 x2 = floatx2{am[i][2*m], am[i][2*m+1]} + cv2[m];
                    floatx2 t2 = x2 * nl2e2;
                    floatx2 e2 = {__builtin_amdgcn_exp2f(t2.x), __builtin_amdgcn_exp2f(t2.y)};
                    floatx2 g2 = {frcp(1.f + e2.x), frcp(1.f + e2.y)};
                    floatx2 hn2 = qc2 * lg2[m] + g2 * hreg2[i][m];
                    hreg2[i][m] = hn2;
                    if (i == 0) vv2[m] = qn2 * hn2;
                    else        vv2[m] = vv2[m] + qn2 * hn2;
                }
            }
            #pragma unroll
            for (int i = 0; i < 2; i++) {
                const int cb = 2*hh + i;
                #pragma unroll
                for (int q = 0; q < 4; q++) {
                    int kb = 2*g + (q>>1);
                    int lanep = l31 + ((q&1) << 5);
                    int off = (((kb*4 + cb) << 10) + lanep*16 + (h5 << 3)) >> 2;
                    uint2 pr = make_uint2(cvtpk(hreg2[i][2*q].x,   hreg2[i][2*q].y),
                                          cvtpk(hreg2[i][2*q+1].x, hreg2[i][2*q+1].y));
                    *(uint2*)(s_frag + off) = pr;
                }
            }
            #pragma unroll
            for (int m = 0; m < 8; m++) {
                int r = 2*m;
                int d = 32*g + (r&3) + 8*(r>>2) + 4*h5;
                s_big[(hh*128 + d)*34 + l31]     = vv2[m].x;
                s_big[(hh*128 + d + 1)*34 + l31] = vv2[m].y;
            }
            if (tid < 128) {
                float c128 = s_redE[tid] + s_redE[128 + tid] + s_pre[pbp][256 + tid];
                float gg = fsig(s_l128[0][tid] + s_l128[1][tid] + c128);
                s_h128[tid] = qc[128]*s_LG[tid] + gg*s_h128[tid];
            }
        }
        wg_barrier();   // BD
        // ---- phW: am(t+1) MFMA + logit(t+1) + qsum(t+2)  ||  htv reduce ----
        #pragma unroll
        for (int i = 0; i < 2; i++) {
            const int cb = 2*hh + i;
            floatx16 a = (floatx16)(0.f);
            #pragma unroll
            for (int kb = 0; kb < 8; kb++) {
                short8v bf = *(const short8v*)((const char*)s_frag +
                               (((kb*4 + cb) << 10) + lane*16));
                a = __builtin_amdgcn_mfma_f32_32x32x16_bf16(
                        __builtin_bit_cast(short8v, afru[kb]), bf, a, 0, 0, 0);
            }
            am[i] = a;
        }
        {
            float part = 0.f;
            #pragma unroll
            for (int kbl = 0; kbl < 4; kbl++) {
                const int kb = 4*hh + kbl;
                const int kb0 = 16*kb + 8*h5;
                uint4 u = afru[kb];
                part += s_h128[kb0+0]*blo(u.x) + s_h128[kb0+1]*bhi(u.x);
                part += s_h128[kb0+2]*blo(u.y) + s_h128[kb0+3]*bhi(u.y);
                part += s_h128[kb0+4]*blo(u.z) + s_h128[kb0+5]*bhi(u.z);
                part += s_h128[kb0+6]*blo(u.w) + s_h128[kb0+7]*bhi(u.w);
            }
            part += __shfl_xor(part, 32);
            if (h5 == 0) s_l128[hh][32*g + l31] = part;
        }
        if (w == 7 && t + 2 <= 99) {
            const float* q2 = s_q[(t + 2) % 3];
            float v = q2[lane] + q2[64 + lane] + ((lane < 32) ? q2[128 + lane] : 0.f);
            #pragma unroll
            for (int m = 32; m > 0; m >>= 1) v += __shfl_xor(v, m);
            if (lane == 0) s_scal[(t + 2) & 1] = v;
        }
        {
            const int row = 16*w + (lane >> 2);
            const int qr  = lane & 3;
            const float* basep = &s_big[(((qr >> 1) << 7) + row)*34 + ((qr & 1) << 4)];
            floatx2 a2 = {0.f, 0.f};
            #pragma unroll
            for (int jj = 0; jj < 8; jj++)
                a2 = a2 + *(const floatx2*)(basep + 2*jj);
            float a0 = a2.x + a2.y;
            a0 += __shfl_xor(a0, 1);
            a0 += __shfl_xor(a0, 2);
            float htvv = (a0 + qn[128]*s_h128[row]) * frcp(s_scal[(t + 1) & 1]);
            if ((lane & 3) == 0)
                HTV[((size_t)b*(SS-1) + t)*128 + row] = __float2half(htvv);
            float oth = __shfl_down(htvv, 4);
            if ((lane & 7) == 0) s_htvb[row >> 1] = cvtpk(htvv, oth);
        }
        wg_barrier();   // BE
    }
}

// ---- K4: y epilogue (parallel over all b,t) ----------------------------------
__global__ __launch_bounds__(128)
void k4_y(const float* __restrict__ W5, float* __restrict__ out,
          const unsigned* __restrict__ ws) {
    const int b = blockIdx.x, t = blockIdx.y, j = threadIdx.x;
    const __half* HTV = (const __half*)(ws + OFF_HTV);
    const __half* PRE = (const __half*)(ws + OFF_PRE);
    __shared__ float s_h[128];
    __shared__ float s_p[2];
    s_h[j] = __half2float(HTV[((size_t)b*(SS-1) + t)*128 + j]);
    __syncthreads();
    float z = __half2float(PRE[(size_t)(b*SS + t)*512 + 384 + j]);
    #pragma unroll 4
    for (int k = 0; k < 128; k++) z += s_h[k] * W5[(size_t)(128 + k)*DK + j];
    float v = fsig(z);
    #pragma unroll
    for (int m = 32; m > 0; m >>= 1) v += __shfl_xor(v, m);
    if ((j & 63) == 0) s_p[j >> 6] = v;
    __syncthreads();
    if (j == 0) {
        out[b*SS + t + 1] = (s_p[0] + s_p[1]) * (1.0f / 128.0f);
        if (t == 0) out[b*SS] = 0.f;
    }
}

extern "C" void kernel_launch(void* const* d_in, const int* in_sizes, int n_in,
                              void* d_out, int out_size, void* d_ws, size_t ws_size,
                              hipStream_t stream) {
    const int*   e_data  = (const int*)d_in[0];
    const int*   a_data  = (const int*)d_in[1];
    const int*   it_data = (const int*)d_in[2];
    const int*   at_data = (const int*)d_in[3];
    const float* qm  = (const float*)d_in[4];
    const float* h0  = (const float*)d_in[5];
    const float* Ee  = (const float*)d_in[6];
    const float* Eat = (const float*)d_in[7];
    const float* Eit = (const float*)d_in[8];
    const float* W1  = (const float*)d_in[9];
    const float* b1  = (const float*)d_in[10];
    const float* W2  = (const float*)d_in[11];
    const float* b2  = (const float*)d_in[12];
    const float* W3  = (const float*)d_in[13];
    const float* b3  = (const float*)d_in[14];
    const float* W4  = (const float*)d_in[15];
    const float* b4  = (const float*)d_in[16];
    const float* W5  = (const float*)d_in[17];
    const float* b5  = (const float*)d_in[18];
    float* out = (float*)d_out;
    unsigned* ws = (unsigned*)d_ws;

    k0_prep<<<dim3((123008 + 255) / 256), dim3(256), 0, stream>>>(W1, W2, W3, W4, W5, ws);
    k1_al<<<dim3(BB, 25), dim3(128), 0, stream>>>(e_data, a_data, at_data, Ee, Eat, b1, ws);
    k2_pre<<<dim3(BB, 25), dim3(512), 0, stream>>>(e_data, it_data, Eit, Ee, b2, b3, b4, b5, ws);
    lpkt_kernel<<<dim3(BB), dim3(NTH), 0, stream>>>(e_data, qm, h0, ws);
    k4_y<<<dim3(BB, SS - 1), dim3(128), 0, stream>>>(W5, out, ws);
}